// Round 1
// baseline (2009.530 us; speedup 1.0000x reference)
//
#include <hip/hip_runtime.h>

// ResUpBlock (StyleGAN2): conv1(3x3,256->256)+FLReLU ; up2x+conv2(3x3,256->128)+FLReLU ;
// skip = up2x + 1x1 ; out = (out2 + skip)/sqrt2.
//
// Decomposition:
//   t1 = lrelu(conv3x3(x, w1/48) + b1) * sqrt2                    [8,256,64,64]  (ws)
//   t2 = conv1x1(x, wsk/16)                                       [8,128,64,64]  (ws)
//   out = upsample2x(t2) / sqrt2                                  (init)
//   out += lrelu(conv3x3(upsample2x(t1), w2/48) + b2)             (u-tile fused in LDS)
//
// All conv kernels: outer-product register tile, 8 couts x 8 px per thread (64 acc),
// block = 256 thr = 64 couts x 256 px, LDS-staged inputs + tap-major weights.

#define SQRT2F  1.41421356237309504880f
#define RSQRT2F 0.70710678118654752440f

__device__ __forceinline__ float lrelu_s(float v) {
    return (v >= 0.f ? v : 0.2f * v);
}

// ---------------------------------------------------------------------------
// Kernel A: t1 = lrelu(conv3x3(x) + b1) * sqrt2     grid (16 ytiles, 4 octiles, 8 n)
// ---------------------------------------------------------------------------
__global__ __launch_bounds__(256, 2) void k_conv1(
    const float* __restrict__ x, const float* __restrict__ w1,
    const float* __restrict__ b1, float* __restrict__ t1)
{
    const int tid    = threadIdx.x;
    const int ytile  = blockIdx.x;        // 0..15 (4 output rows each)
    const int oc0    = blockIdx.y << 6;   // 0,64,128,192
    const int n      = blockIdx.z;        // 0..7
    const int oc_grp = tid & 7;           // 8 couts each
    const int sp     = tid >> 3;          // 0..31
    const int row    = sp >> 3;           // 0..3
    const int x0     = (sp & 7) << 3;     // 0..56
    const int y0     = ytile << 2;

    __shared__ float tile[4][6][68];      // 4 cin x (4+2 halo rows) x (66 used, pad 68)
    __shared__ float wlds[4][9][64];      // 4 cin x 9 taps x 64 couts (tap-major)

    float acc[8][8];
#pragma unroll
    for (int i = 0; i < 8; ++i)
#pragma unroll
        for (int j = 0; j < 8; ++j) acc[i][j] = 0.f;

    for (int c0 = 0; c0 < 256; c0 += 4) {
        // stage input: 4*6*66 = 1584 values, zero outside [0,64)^2 (pad=1)
        for (int idx = tid; idx < 1584; idx += 256) {
            int c   = idx / 396;
            int rem = idx - c * 396;
            int r   = rem / 66;
            int cc  = rem - r * 66;
            int gy  = y0 - 1 + r;
            int gx  = cc - 1;
            float v = 0.f;
            if ((unsigned)gy < 64u && (unsigned)gx < 64u)
                v = x[((size_t)(n * 256 + c0 + c) * 64 + gy) * 64 + gx];
            tile[c][r][cc] = v;
        }
        // stage weights (scale 1/sqrt(256*9) = 1/48 folded in): 4*576 = 2304
        for (int idx = tid; idx < 2304; idx += 256) {
            int c   = idx / 576;
            int rem = idx - c * 576;
            int tap = rem >> 6;
            int oc  = rem & 63;
            wlds[c][tap][oc] = w1[((size_t)(oc0 + oc) * 256 + c0 + c) * 9 + tap] * (1.0f / 48.0f);
        }
        __syncthreads();
#pragma unroll 1
        for (int c = 0; c < 4; ++c) {
            float win[3][10];
#pragma unroll
            for (int dy = 0; dy < 3; ++dy) {
                const float* tr = &tile[c][row + dy][x0];
#pragma unroll
                for (int j = 0; j < 10; ++j) win[dy][j] = tr[j];
            }
#pragma unroll
            for (int ky = 0; ky < 3; ++ky)
#pragma unroll
            for (int kx = 0; kx < 3; ++kx) {
                float wv[8];
                const float* wr = &wlds[c][ky * 3 + kx][oc_grp << 3];
#pragma unroll
                for (int i = 0; i < 8; ++i) wv[i] = wr[i];
#pragma unroll
                for (int i = 0; i < 8; ++i)
#pragma unroll
                    for (int j = 0; j < 8; ++j)
                        acc[i][j] = fmaf(wv[i], win[ky][j + kx], acc[i][j]);
            }
        }
        __syncthreads();
    }

    const int y = y0 + row;
#pragma unroll
    for (int i = 0; i < 8; ++i) {
        int oc = oc0 + (oc_grp << 3) + i;
        float bias = b1[oc];
        float* dst = t1 + ((size_t)(n * 256 + oc) * 64 + y) * 64 + x0;
#pragma unroll
        for (int j = 0; j < 8; ++j) {
            float v = acc[i][j] + bias;
            dst[j] = lrelu_s(v) * SQRT2F;
        }
    }
}

// ---------------------------------------------------------------------------
// Kernel B1: t2 = conv1x1(x, wsk/16)      grid (16 ytiles, 2 octiles, 8 n)
// ---------------------------------------------------------------------------
__global__ __launch_bounds__(256, 2) void k_skip1x1(
    const float* __restrict__ x, const float* __restrict__ wsk, float* __restrict__ t2)
{
    const int tid    = threadIdx.x;
    const int ytile  = blockIdx.x;
    const int oc0    = blockIdx.y << 6;
    const int n      = blockIdx.z;
    const int oc_grp = tid & 7;
    const int sp     = tid >> 3;
    const int row    = sp >> 3;
    const int x0     = (sp & 7) << 3;
    const int y0     = ytile << 2;

    __shared__ float xt[8][4][64];
    __shared__ float wl[8][64];

    float acc[8][8];
#pragma unroll
    for (int i = 0; i < 8; ++i)
#pragma unroll
        for (int j = 0; j < 8; ++j) acc[i][j] = 0.f;

    for (int c0 = 0; c0 < 256; c0 += 8) {
        for (int idx = tid; idx < 2048; idx += 256) {
            int c = idx >> 8;
            int rem = idx & 255;
            xt[c][rem >> 6][rem & 63] =
                x[((size_t)(n * 256 + c0 + c) * 64 + y0 + (rem >> 6)) * 64 + (rem & 63)];
        }
        for (int idx = tid; idx < 512; idx += 256) {
            int c = idx >> 6;
            int oc = idx & 63;
            wl[c][oc] = wsk[(size_t)(oc0 + oc) * 256 + c0 + c] * (1.0f / 16.0f);
        }
        __syncthreads();
#pragma unroll 1
        for (int c = 0; c < 8; ++c) {
            float inv[8], wv[8];
            const float* xr = &xt[c][row][x0];
            const float* wr = &wl[c][oc_grp << 3];
#pragma unroll
            for (int j = 0; j < 8; ++j) inv[j] = xr[j];
#pragma unroll
            for (int i = 0; i < 8; ++i) wv[i] = wr[i];
#pragma unroll
            for (int i = 0; i < 8; ++i)
#pragma unroll
                for (int j = 0; j < 8; ++j)
                    acc[i][j] = fmaf(wv[i], inv[j], acc[i][j]);
        }
        __syncthreads();
    }

    const int y = y0 + row;
#pragma unroll
    for (int i = 0; i < 8; ++i) {
        int oc = oc0 + (oc_grp << 3) + i;
        float* dst = t2 + ((size_t)(n * 128 + oc) * 64 + y) * 64 + x0;
#pragma unroll
        for (int j = 0; j < 8; ++j) dst[j] = acc[i][j];
    }
}

// ---------------------------------------------------------------------------
// Kernel B2: out = upsample2x_bilinear(t2) / sqrt2   (writes EVERY out element)
// ---------------------------------------------------------------------------
__global__ __launch_bounds__(256) void k_upskip(
    const float* __restrict__ t2, float* __restrict__ out)
{
    size_t idx = (size_t)blockIdx.x * 256 + threadIdx.x;   // 16777216 total
    int ox = (int)(idx & 127);
    int oy = (int)((idx >> 7) & 127);
    int nc = (int)(idx >> 14);                              // n*128 + oc, 0..1023

    int m = oy >> 1, k = ox >> 1;
    int ry0, ry1, cx0, cx1;
    float wy0, wy1, wx0, wx1;
    if (oy & 1) { ry0 = m; ry1 = (m + 1 > 63) ? 63 : m + 1; wy0 = 0.75f; wy1 = 0.25f; }
    else        { ry0 = (m - 1 < 0) ? 0 : m - 1; ry1 = m;   wy0 = 0.25f; wy1 = 0.75f; }
    if (ox & 1) { cx0 = k; cx1 = (k + 1 > 63) ? 63 : k + 1; wx0 = 0.75f; wx1 = 0.25f; }
    else        { cx0 = (k - 1 < 0) ? 0 : k - 1; cx1 = k;   wx0 = 0.25f; wx1 = 0.75f; }

    const float* p = t2 + (size_t)nc * 4096;
    float v = wy0 * (wx0 * p[ry0 * 64 + cx0] + wx1 * p[ry0 * 64 + cx1])
            + wy1 * (wx0 * p[ry1 * 64 + cx0] + wx1 * p[ry1 * 64 + cx1]);
    out[idx] = v * RSQRT2F;
}

// ---------------------------------------------------------------------------
// Kernel C: out += lrelu(conv3x3(upsample2x(t1), w2/48) + b2)
//   u-tile (4 rows x 130 cols of the virtual 128x128 upsampled grid, zero pad
//   outside, bilinear edge-clamped inside) synthesized into LDS per cin chunk.
//   grid (64 oytiles of 2 rows, 2 octiles, 8 n)
// ---------------------------------------------------------------------------
__global__ __launch_bounds__(256, 2) void k_conv2(
    const float* __restrict__ t1, const float* __restrict__ w2,
    const float* __restrict__ b2, float* __restrict__ out)
{
    const int tid    = threadIdx.x;
    const int oytile = blockIdx.x;        // 0..63 (2 output rows each)
    const int oc0    = blockIdx.y << 6;   // 0,64
    const int n      = blockIdx.z;
    const int oc_grp = tid & 7;
    const int sp     = tid >> 3;          // 0..31
    const int row    = sp >> 4;           // 0..1
    const int x0     = (sp & 15) << 3;    // 0..120
    const int oy0    = oytile << 1;

    __shared__ float utile[4][4][132];    // 4 cin x 4 u-rows x (130 used, pad 132)
    __shared__ float wlds[4][9][64];

    float acc[8][8];
#pragma unroll
    for (int i = 0; i < 8; ++i)
#pragma unroll
        for (int j = 0; j < 8; ++j) acc[i][j] = 0.f;

    for (int c0 = 0; c0 < 256; c0 += 4) {
        // synthesize u-tile: rows oy0-1..oy0+2, cols -1..128 of upsampled t1
        for (int idx = tid; idx < 2080; idx += 256) {
            int c   = idx / 520;
            int rem = idx - c * 520;
            int r   = rem / 130;
            int cc  = rem - r * 130;
            int oy  = oy0 - 1 + r;
            int ox  = cc - 1;
            float v = 0.f;
            if ((unsigned)oy < 128u && (unsigned)ox < 128u) {
                int m = oy >> 1, k = ox >> 1;
                int ry0, ry1, cx0, cx1;
                float wy0, wy1, wx0, wx1;
                if (oy & 1) { ry0 = m; ry1 = (m + 1 > 63) ? 63 : m + 1; wy0 = 0.75f; wy1 = 0.25f; }
                else        { ry0 = (m - 1 < 0) ? 0 : m - 1; ry1 = m;   wy0 = 0.25f; wy1 = 0.75f; }
                if (ox & 1) { cx0 = k; cx1 = (k + 1 > 63) ? 63 : k + 1; wx0 = 0.75f; wx1 = 0.25f; }
                else        { cx0 = (k - 1 < 0) ? 0 : k - 1; cx1 = k;   wx0 = 0.25f; wx1 = 0.75f; }
                const float* p = t1 + (size_t)(n * 256 + c0 + c) * 4096;
                v = wy0 * (wx0 * p[ry0 * 64 + cx0] + wx1 * p[ry0 * 64 + cx1])
                  + wy1 * (wx0 * p[ry1 * 64 + cx0] + wx1 * p[ry1 * 64 + cx1]);
            }
            utile[c][r][cc] = v;
        }
        for (int idx = tid; idx < 2304; idx += 256) {
            int c   = idx / 576;
            int rem = idx - c * 576;
            int tap = rem >> 6;
            int oc  = rem & 63;
            wlds[c][tap][oc] = w2[((size_t)(oc0 + oc) * 256 + c0 + c) * 9 + tap] * (1.0f / 48.0f);
        }
        __syncthreads();
#pragma unroll 1
        for (int c = 0; c < 4; ++c) {
            float win[3][10];
#pragma unroll
            for (int dy = 0; dy < 3; ++dy) {
                const float* ur = &utile[c][row + dy][x0];
#pragma unroll
                for (int j = 0; j < 10; ++j) win[dy][j] = ur[j];
            }
#pragma unroll
            for (int ky = 0; ky < 3; ++ky)
#pragma unroll
            for (int kx = 0; kx < 3; ++kx) {
                float wv[8];
                const float* wr = &wlds[c][ky * 3 + kx][oc_grp << 3];
#pragma unroll
                for (int i = 0; i < 8; ++i) wv[i] = wr[i];
#pragma unroll
                for (int i = 0; i < 8; ++i)
#pragma unroll
                    for (int j = 0; j < 8; ++j)
                        acc[i][j] = fmaf(wv[i], win[ky][j + kx], acc[i][j]);
            }
        }
        __syncthreads();
    }

    const int oy = oy0 + row;
#pragma unroll
    for (int i = 0; i < 8; ++i) {
        int oc = oc0 + (oc_grp << 3) + i;
        float bias = b2[oc];
        float* dst = out + ((size_t)(n * 128 + oc) * 128 + oy) * 128 + x0;
#pragma unroll
        for (int j = 0; j < 8; ++j) {
            float v = acc[i][j] + bias;
            dst[j] += lrelu_s(v);   // (lrelu*sqrt2 + skip)/sqrt2 == lrelu + skip/sqrt2
        }
    }
}

// ---------------------------------------------------------------------------
extern "C" void kernel_launch(void* const* d_in, const int* in_sizes, int n_in,
                              void* d_out, int out_size, void* d_ws, size_t ws_size,
                              hipStream_t stream)
{
    const float* x   = (const float*)d_in[0];
    const float* w1  = (const float*)d_in[1];
    const float* b1  = (const float*)d_in[2];
    const float* w2  = (const float*)d_in[3];
    const float* b2  = (const float*)d_in[4];
    const float* wsk = (const float*)d_in[5];
    float* out = (float*)d_out;

    float* t1 = (float*)d_ws;                          // 8*256*64*64 = 33.5 MB
    float* t2 = t1 + (size_t)8 * 256 * 64 * 64;        // 8*128*64*64 = 16.8 MB

    k_conv1  <<<dim3(16, 4, 8),    256, 0, stream>>>(x, w1, b1, t1);
    k_skip1x1<<<dim3(16, 2, 8),    256, 0, stream>>>(x, wsk, t2);
    k_upskip <<<dim3(65536, 1, 1), 256, 0, stream>>>(t2, out);
    k_conv2  <<<dim3(64, 2, 8),    256, 0, stream>>>(t1, w2, b2, out);
}

// Round 2
// 462.710 us; speedup vs baseline: 4.3430x; 4.3430x over previous
//
#include <hip/hip_runtime.h>
#include <hip/hip_bf16.h>

// ResUpBlock via bf16 MFMA implicit GEMM (fp32 accumulate).
//   xT  = channels-last bf16 copy of x              [8][64][64][256]
//   t1  = lrelu(conv3x3(x,w1/48)+b1)*sqrt2 -> bf16  [8][64][64][256] (channels-last)
//   t2  = conv1x1(x, wsk/16)              -> bf16   [8][64][64][128] (channels-last)
//   out = upsample2x(t2)/sqrt2                      (k_upskip, NCHW f32)
//   out += lrelu(conv3x3(upsample2x(t1), w2/48)+b2) (k_conv2, u-tile synthesized in LDS)
// GEMM mapping (conv1/conv2): C[m=oc][n=px], A=weights [oc][tap][c] (global, L2-hot),
// B=data channels-last tiles in LDS (c-chunks of 32, padded to 40 -> conflict-free b128).
// mfma_f32_16x16x32_bf16: A/B frag = 8 contiguous k per lane (k=quad*8+j, lane&15=m/n),
// C/D: col=lane&15, row=quad*4+reg (verified layouts per guide m89/m120).

typedef __attribute__((ext_vector_type(8))) short bf16x8;
typedef __attribute__((ext_vector_type(4))) float f32x4;

#define SQRT2F  1.41421356237309504880f
#define RSQRT2F 0.70710678118654752440f

__device__ __forceinline__ float lrelu_s(float v) { return v >= 0.f ? v : 0.2f * v; }

__device__ __forceinline__ unsigned short f2bf(float f) {
    unsigned u = __builtin_bit_cast(unsigned, f);
    u += 0x7fffu + ((u >> 16) & 1u);          // RNE
    return (unsigned short)(u >> 16);
}
__device__ __forceinline__ float bflo(unsigned u) {
    return __builtin_bit_cast(float, u << 16);
}
__device__ __forceinline__ float bfhi(unsigned u) {
    return __builtin_bit_cast(float, u & 0xffff0000u);
}

// bilinear 2x coefficients (align_corners=False, matches jax.image.resize; edge-clamped)
__device__ __forceinline__ void up2_coef(int o, int lim, int& i0, int& i1, float& w0, float& w1) {
    int h = o >> 1;
    if (o & 1) { i0 = h; i1 = (h + 1 > lim) ? lim : h + 1; w0 = 0.75f; w1 = 0.25f; }
    else       { i0 = (h - 1 < 0) ? 0 : h - 1; i1 = h;     w0 = 0.25f; w1 = 0.75f; }
}

// ---------------------------------------------------------------------------
// weight transforms
// ---------------------------------------------------------------------------
__global__ __launch_bounds__(256) void k_wt3(const float* __restrict__ w,
                                             unsigned short* __restrict__ wt,
                                             int total, float scale) {
    int i = blockIdx.x * 256 + threadIdx.x;           // i over OC*9*256, layout [oc][tap][c]
    if (i >= total) return;
    int c = i & 255; int rem = i >> 8; int tap = rem % 9; int oc = rem / 9;
    wt[i] = f2bf(w[(oc * 256 + c) * 9 + tap] * scale);
}

__global__ __launch_bounds__(256) void k_wt1(const float* __restrict__ w,
                                             unsigned short* __restrict__ wt,
                                             int total, float scale) {
    int i = blockIdx.x * 256 + threadIdx.x;           // [oc][c] identity layout
    if (i >= total) return;
    wt[i] = f2bf(w[i] * scale);
}

// ---------------------------------------------------------------------------
// x (NCHW f32) -> xT (channels-last bf16) via LDS transpose
// grid (64 px-tiles, 4 c-tiles, 8 n)
// ---------------------------------------------------------------------------
__global__ __launch_bounds__(256) void k_xprep(const float* __restrict__ x,
                                               unsigned short* __restrict__ xT) {
    __shared__ float t[64][65];
    const int n = blockIdx.z, c0 = blockIdx.y << 6, p0 = blockIdx.x << 6;
    for (int i = threadIdx.x; i < 4096; i += 256) {
        int c = i >> 6, p = i & 63;
        t[c][p] = x[((size_t)(n * 256 + c0 + c) << 12) + p0 + p];
    }
    __syncthreads();
    for (int i = threadIdx.x; i < 4096; i += 256) {
        int p = i >> 6, c = i & 63;
        xT[((size_t)((n << 12) + p0 + p) << 8) + c0 + c] = f2bf(t[c][p]);
    }
}

// ---------------------------------------------------------------------------
// conv1: t1 = lrelu(conv3x3(x)+b1)*sqrt2, bf16 channels-last.
// block: M=64 oc x N=256 px (4 rows x 64 cols); wave w owns row y0+w.
// grid dim3(128, 4): bx -> (n, ytile), by -> oc-block
// ---------------------------------------------------------------------------
__global__ __launch_bounds__(256, 2) void k_conv1(
    const unsigned short* __restrict__ xT, const unsigned short* __restrict__ w1T,
    const float* __restrict__ b1, unsigned short* __restrict__ t1)
{
    __shared__ __align__(16) unsigned short dt[6][66][40];   // 31.7 KB, c padded 32->40
    const int tid = threadIdx.x;
    const int n   = blockIdx.x >> 4;
    const int y0  = (blockIdx.x & 15) << 2;
    const int oc0 = blockIdx.y << 6;
    const int w   = tid >> 6;
    const int m   = tid & 15;
    const int q   = (tid & 63) >> 4;

    f32x4 acc[4][4];
#pragma unroll
    for (int a = 0; a < 4; ++a)
#pragma unroll
        for (int g = 0; g < 4; ++g) acc[a][g] = (f32x4){0.f, 0.f, 0.f, 0.f};

    const unsigned short* wbase = w1T + (oc0 + m) * 2304 + (q << 3);

    for (int c0 = 0; c0 < 256; c0 += 32) {
        // stage data tile: rows y0-1..y0+4, cols -1..64, 32 channels (vec8 groups)
        for (int idx = tid; idx < 1584; idx += 256) {
            int r = idx / 264; int rem = idx - r * 264; int col = rem >> 2; int g = rem & 3;
            int gy = y0 - 1 + r, gx = col - 1;
            uint4 v = make_uint4(0, 0, 0, 0);
            if ((unsigned)gy < 64u && (unsigned)gx < 64u)
                v = *(const uint4*)(xT + (((n << 12) + (gy << 6) + gx) << 8) + c0 + (g << 3));
            *(uint4*)(&dt[r][col][g << 3]) = v;
        }
        __syncthreads();

        uint4 aq[2][4];
#pragma unroll
        for (int a = 0; a < 4; ++a)
            aq[0][a] = *(const uint4*)(wbase + a * (16 * 2304) + c0);   // tap 0
#pragma unroll
        for (int tap = 0; tap < 9; ++tap) {
            const int cur = tap & 1;
            if (tap < 8) {
#pragma unroll
                for (int a = 0; a < 4; ++a)
                    aq[cur ^ 1][a] = *(const uint4*)(wbase + a * (16 * 2304) + (tap + 1) * 256 + c0);
            }
            const int dy = tap / 3, dx = tap - 3 * (tap / 3);
            bf16x8 bfr[4];
#pragma unroll
            for (int g = 0; g < 4; ++g)
                bfr[g] = *(const bf16x8*)(&dt[w + dy][(g << 4) + m + dx][q << 3]);
#pragma unroll
            for (int a = 0; a < 4; ++a) {
                bf16x8 af = __builtin_bit_cast(bf16x8, aq[cur][a]);
#pragma unroll
                for (int g = 0; g < 4; ++g)
                    acc[a][g] = __builtin_amdgcn_mfma_f32_16x16x32_bf16(af, bfr[g], acc[a][g], 0, 0, 0);
            }
        }
        __syncthreads();
    }

    // epilogue: lane holds 4 consecutive oc (q*4+r) at px (g*16+m) -> 8B bf16 stores
    const int y = y0 + w;
#pragma unroll
    for (int a = 0; a < 4; ++a) {
        const int oc = oc0 + (a << 4) + (q << 2);
        float b0 = b1[oc], b1v = b1[oc + 1], b2v = b1[oc + 2], b3 = b1[oc + 3];
#pragma unroll
        for (int g = 0; g < 4; ++g) {
            const int xcol = (g << 4) + m;
            unsigned lo = (unsigned)f2bf(lrelu_s(acc[a][g][0] + b0) * SQRT2F)
                        | ((unsigned)f2bf(lrelu_s(acc[a][g][1] + b1v) * SQRT2F) << 16);
            unsigned hi = (unsigned)f2bf(lrelu_s(acc[a][g][2] + b2v) * SQRT2F)
                        | ((unsigned)f2bf(lrelu_s(acc[a][g][3] + b3) * SQRT2F) << 16);
            uint2 s; s.x = lo; s.y = hi;
            *(uint2*)(t1 + (((n << 12) + (y << 6) + xcol) << 8) + oc) = s;
        }
    }
}

// ---------------------------------------------------------------------------
// skip GEMM: t2[px][oc] = sum_c xT[px][c]*wsT[oc][c]  (M=px so stores are oc-runs)
// block: 64 px (wave=16 px) x 128 oc; grid 512
// ---------------------------------------------------------------------------
__global__ __launch_bounds__(256, 2) void k_skip(
    const unsigned short* __restrict__ xT, const unsigned short* __restrict__ wsT,
    unsigned short* __restrict__ t2)
{
    const int tid = threadIdx.x;
    const int w = tid >> 6, m = tid & 15, q = (tid & 63) >> 4;
    const int px0 = blockIdx.x << 6;
    const int apx = px0 + (w << 4) + m;

    f32x4 acc[8];
#pragma unroll
    for (int g = 0; g < 8; ++g) acc[g] = (f32x4){0.f, 0.f, 0.f, 0.f};

#pragma unroll
    for (int c0 = 0; c0 < 256; c0 += 32) {
        bf16x8 af = *(const bf16x8*)(xT + ((size_t)apx << 8) + c0 + (q << 3));
#pragma unroll
        for (int g = 0; g < 8; ++g) {
            bf16x8 bf = *(const bf16x8*)(wsT + (((g << 4) + m) << 8) + c0 + (q << 3));
            acc[g] = __builtin_amdgcn_mfma_f32_16x16x32_bf16(af, bf, acc[g], 0, 0, 0);
        }
    }
#pragma unroll
    for (int g = 0; g < 8; ++g) {
        const int oc = (g << 4) + m;
#pragma unroll
        for (int r = 0; r < 4; ++r) {
            int opx = px0 + (w << 4) + (q << 2) + r;
            t2[((size_t)opx << 7) + oc] = f2bf(acc[g][r]);
        }
    }
}

// ---------------------------------------------------------------------------
// out = upsample2x(t2)/sqrt2 (initializes every NCHW element)
// grid dim3(8, 128, 8); thread = (oc-octet, ox within 16-run)
// ---------------------------------------------------------------------------
__global__ __launch_bounds__(256) void k_upskip(
    const unsigned short* __restrict__ t2, float* __restrict__ out)
{
    const int tid = threadIdx.x;
    const int oc8 = tid & 15, oxi = tid >> 4;
    const int ox = (blockIdx.x << 4) + oxi;
    const int oy = blockIdx.y;
    const int n  = blockIdx.z;

    int ry0, ry1, cx0, cx1; float wy0, wy1, wx0, wx1;
    up2_coef(oy, 63, ry0, ry1, wy0, wy1);
    up2_coef(ox, 63, cx0, cx1, wx0, wx1);

    const unsigned short* base = t2 + ((size_t)n << 19);   // n*4096*128
    const int co = oc8 << 3;
    uint4 v00 = *(const uint4*)(base + (((ry0 << 6) + cx0) << 7) + co);
    uint4 v01 = *(const uint4*)(base + (((ry0 << 6) + cx1) << 7) + co);
    uint4 v10 = *(const uint4*)(base + (((ry1 << 6) + cx0) << 7) + co);
    uint4 v11 = *(const uint4*)(base + (((ry1 << 6) + cx1) << 7) + co);
    const unsigned* pa = (const unsigned*)&v00; const unsigned* pb = (const unsigned*)&v01;
    const unsigned* pc = (const unsigned*)&v10; const unsigned* pd = (const unsigned*)&v11;

    float* o = out + ((size_t)(((n << 7) + co) << 7) + oy) * 128 + ox;
#pragma unroll
    for (int j = 0; j < 4; ++j) {
        float vlo = wy0 * (wx0 * bflo(pa[j]) + wx1 * bflo(pb[j]))
                  + wy1 * (wx0 * bflo(pc[j]) + wx1 * bflo(pd[j]));
        float vhi = wy0 * (wx0 * bfhi(pa[j]) + wx1 * bfhi(pb[j]))
                  + wy1 * (wx0 * bfhi(pc[j]) + wx1 * bfhi(pd[j]));
        o[(size_t)(2 * j) * 16384]     = vlo * RSQRT2F;
        o[(size_t)(2 * j + 1) * 16384] = vhi * RSQRT2F;
    }
}

// ---------------------------------------------------------------------------
// conv2: out += lrelu(conv3x3(upsample2x(t1))+b2). u-tile synthesized in LDS.
// block: M=64 oc x N=256 px (2 out rows x 128 cols); wave: (row pair half, x half)
// grid dim3(512, 2): bx -> (n, oy-pair), by -> oc-block
// ---------------------------------------------------------------------------
__global__ __launch_bounds__(256, 2) void k_conv2(
    const unsigned short* __restrict__ t1, const unsigned short* __restrict__ w2T,
    const float* __restrict__ b2, float* __restrict__ out)
{
    __shared__ __align__(16) unsigned short ut[4][130][40];  // 41.6 KB
    const int tid  = threadIdx.x;
    const int n    = blockIdx.x >> 6;
    const int oy0  = (blockIdx.x & 63) << 1;
    const int oc0  = blockIdx.y << 6;
    const int w    = tid >> 6;
    const int m    = tid & 15;
    const int q    = (tid & 63) >> 4;
    const int wrow = w >> 1;
    const int wxh  = (w & 1) << 6;

    f32x4 acc[4][4];
#pragma unroll
    for (int a = 0; a < 4; ++a)
#pragma unroll
        for (int g = 0; g < 4; ++g) acc[a][g] = (f32x4){0.f, 0.f, 0.f, 0.f};

    const unsigned short* wbase = w2T + (oc0 + m) * 2304 + (q << 3);
    const unsigned short* tb    = t1 + ((size_t)n << 20);    // n*4096*256

    for (int c0 = 0; c0 < 256; c0 += 32) {
        // synthesize u-tile rows oy0-1..oy0+2, cols -1..128 (bilinear of t1, zero outside)
        for (int idx = tid; idx < 2080; idx += 256) {
            int r = idx / 520; int rem = idx - r * 520; int col = rem >> 2; int g = rem & 3;
            int oy = oy0 - 1 + r, ox = col - 1;
            uint4 res = make_uint4(0, 0, 0, 0);
            if ((unsigned)oy < 128u && (unsigned)ox < 128u) {
                int ry0, ry1, cx0, cx1; float wy0, wy1, wx0, wx1;
                up2_coef(oy, 63, ry0, ry1, wy0, wy1);
                up2_coef(ox, 63, cx0, cx1, wx0, wx1);
                const int co = c0 + (g << 3);
                uint4 v00 = *(const uint4*)(tb + (((ry0 << 6) + cx0) << 8) + co);
                uint4 v01 = *(const uint4*)(tb + (((ry0 << 6) + cx1) << 8) + co);
                uint4 v10 = *(const uint4*)(tb + (((ry1 << 6) + cx0) << 8) + co);
                uint4 v11 = *(const uint4*)(tb + (((ry1 << 6) + cx1) << 8) + co);
                const unsigned* pa = (const unsigned*)&v00; const unsigned* pb = (const unsigned*)&v01;
                const unsigned* pc = (const unsigned*)&v10; const unsigned* pd = (const unsigned*)&v11;
                unsigned* pr = (unsigned*)&res;
#pragma unroll
                for (int j = 0; j < 4; ++j) {
                    float vlo = wy0 * (wx0 * bflo(pa[j]) + wx1 * bflo(pb[j]))
                              + wy1 * (wx0 * bflo(pc[j]) + wx1 * bflo(pd[j]));
                    float vhi = wy0 * (wx0 * bfhi(pa[j]) + wx1 * bfhi(pb[j]))
                              + wy1 * (wx0 * bfhi(pc[j]) + wx1 * bfhi(pd[j]));
                    pr[j] = (unsigned)f2bf(vlo) | ((unsigned)f2bf(vhi) << 16);
                }
            }
            *(uint4*)(&ut[r][col][g << 3]) = res;
        }
        __syncthreads();

        uint4 aq[2][4];
#pragma unroll
        for (int a = 0; a < 4; ++a)
            aq[0][a] = *(const uint4*)(wbase + a * (16 * 2304) + c0);
#pragma unroll
        for (int tap = 0; tap < 9; ++tap) {
            const int cur = tap & 1;
            if (tap < 8) {
#pragma unroll
                for (int a = 0; a < 4; ++a)
                    aq[cur ^ 1][a] = *(const uint4*)(wbase + a * (16 * 2304) + (tap + 1) * 256 + c0);
            }
            const int dy = tap / 3, dx = tap - 3 * (tap / 3);
            bf16x8 bfr[4];
#pragma unroll
            for (int g = 0; g < 4; ++g)
                bfr[g] = *(const bf16x8*)(&ut[wrow + dy][wxh + (g << 4) + m + dx][q << 3]);
#pragma unroll
            for (int a = 0; a < 4; ++a) {
                bf16x8 af = __builtin_bit_cast(bf16x8, aq[cur][a]);
#pragma unroll
                for (int g = 0; g < 4; ++g)
                    acc[a][g] = __builtin_amdgcn_mfma_f32_16x16x32_bf16(af, bfr[g], acc[a][g], 0, 0, 0);
            }
        }
        __syncthreads();
    }

    // epilogue: out[n][oc][oy][ox] += lrelu(acc + b2)  (out pre-init = skip/sqrt2)
    const int oy = oy0 + wrow;
#pragma unroll
    for (int a = 0; a < 4; ++a) {
        const int oc = oc0 + (a << 4) + (q << 2);
        float bb[4] = {b2[oc], b2[oc + 1], b2[oc + 2], b2[oc + 3]};
#pragma unroll
        for (int g = 0; g < 4; ++g) {
            const int ox = wxh + (g << 4) + m;
            float* p = out + (size_t)((((n << 7) + oc) << 7) + oy) * 128 + ox;
#pragma unroll
            for (int r = 0; r < 4; ++r)
                p[(size_t)r * 16384] += lrelu_s(acc[a][g][r] + bb[r]);
        }
    }
}

// ---------------------------------------------------------------------------
extern "C" void kernel_launch(void* const* d_in, const int* in_sizes, int n_in,
                              void* d_out, int out_size, void* d_ws, size_t ws_size,
                              hipStream_t stream)
{
    const float* x   = (const float*)d_in[0];
    const float* w1  = (const float*)d_in[1];
    const float* b1  = (const float*)d_in[2];
    const float* w2  = (const float*)d_in[3];
    const float* b2  = (const float*)d_in[4];
    const float* wsk = (const float*)d_in[5];
    float* out = (float*)d_out;

    unsigned short* xT  = (unsigned short*)d_ws;        // 8,388,608
    unsigned short* t1  = xT + 8388608;                 // 8,388,608
    unsigned short* t2  = t1 + 8388608;                 // 4,194,304
    unsigned short* w1T = t2 + 4194304;                 // 589,824
    unsigned short* w2T = w1T + 589824;                 // 294,912
    unsigned short* wsT = w2T + 294912;                 // 32,768   (total 43.8 MB)

    k_wt3   <<<dim3(2304), 256, 0, stream>>>(w1, w1T, 589824, 1.0f / 48.0f);
    k_wt3   <<<dim3(1152), 256, 0, stream>>>(w2, w2T, 294912, 1.0f / 48.0f);
    k_wt1   <<<dim3(128),  256, 0, stream>>>(wsk, wsT, 32768, 1.0f / 16.0f);
    k_xprep <<<dim3(64, 4, 8), 256, 0, stream>>>(x, xT);
    k_conv1 <<<dim3(128, 4), 256, 0, stream>>>(xT, w1T, b1, t1);
    k_skip  <<<dim3(512), 256, 0, stream>>>(xT, wsT, t2);
    k_upskip<<<dim3(8, 128, 8), 256, 0, stream>>>(t2, out);
    k_conv2 <<<dim3(512, 2), 256, 0, stream>>>(t1, w2T, b2, out);
}